// Round 2
// baseline (763.431 us; speedup 1.0000x reference)
//
#include <hip/hip_runtime.h>
#include <hip/hip_bf16.h>

// TTT layer, one gradient step, fused, round 2.
// out = S - c * ((relu'(z) .* (h@G + c2 - T@W2^T)) @ W1^T)
//   z = S@W1 + b1, h = relu(z), G = W2@W2^T (symmetric), c2 = W2@b2
//   c = lr * 2 / (B*T*H). Stability-term gradient is zero at step 1.

#define Hdim 1024
#define Ddim 256
#define NTOK 32768
#define MT   32          // tokens per block

typedef __attribute__((ext_vector_type(8))) short bf16x8;
typedef __attribute__((ext_vector_type(4))) float f32x4;

static __device__ __forceinline__ unsigned short f2bf(float f) {
    unsigned u = __builtin_bit_cast(unsigned, f);
    u += 0x7FFFu + ((u >> 16) & 1u);          // RNE
    return (unsigned short)(u >> 16);
}

// bf16 weight layouts (B-operand = contiguous 16B per lane at [col][k]):
//  w1t [d][h] : phase A  (h = S@W1,  col=d, k=h)
//  w2b [d][h] : phase B' (u = T@W2^T, col=d, k=h)  == native W2 layout
//  w1b [h][d] : phase D  (g = dh@W1^T, col=h, k=d) == native W1 layout
__global__ void prep_weights(const float* __restrict__ W1, const float* __restrict__ W2,
                             unsigned short* __restrict__ w1t,
                             unsigned short* __restrict__ w2b,
                             unsigned short* __restrict__ w1b) {
    int i = blockIdx.x * blockDim.x + threadIdx.x;
    if (i >= Hdim * Ddim) return;
    int h = i >> 8, d = i & 255;              // i as (h,d)
    unsigned short v1 = f2bf(W1[i]);
    w1b[i] = v1;
    w1t[d * Hdim + h] = v1;
    w2b[i] = f2bf(W2[i]);                     // i as (d,h), native
}

// G[d][t] = sum_h W2[d][h]*W2[t][h]  (bf16), and c2[d] = sum_h b2[h]*W2[d][h]
__global__ void prep_G(const float* __restrict__ W2, const float* __restrict__ b2,
                       unsigned short* __restrict__ Gb, float* __restrict__ c2) {
    __shared__ float wd[Hdim];
    __shared__ float red[4];
    const int d = blockIdx.x;
    const int t = threadIdx.x;                // 256 threads
    float4 v = *(const float4*)(W2 + (size_t)d * Hdim + t * 4);
    *(float4*)(wd + t * 4) = v;
    __syncthreads();
    const float* wp = W2 + (size_t)t * Hdim;  // row t
    float s = 0.f;
    for (int h = 0; h < Hdim; h += 4) {
        float4 a = *(const float4*)(wp + h);
        s += a.x * wd[h] + a.y * wd[h + 1] + a.z * wd[h + 2] + a.w * wd[h + 3];
    }
    Gb[d * Ddim + t] = f2bf(s);
    // c2 partial: this block's row d dotted with b2
    float4 bb = *(const float4*)(b2 + t * 4);
    float p = bb.x * wd[t * 4] + bb.y * wd[t * 4 + 1] + bb.z * wd[t * 4 + 2] + bb.w * wd[t * 4 + 3];
    #pragma unroll
    for (int o = 32; o > 0; o >>= 1) p += __shfl_down(p, o);
    if ((t & 63) == 0) red[t >> 6] = p;
    __syncthreads();
    if (t == 0) c2[d] = red[0] + red[1] + red[2] + red[3];
}

__launch_bounds__(512, 4)
__global__ void ttt_fused(const float* __restrict__ state,
                          const float* __restrict__ target,
                          const float* __restrict__ b1,
                          const float* __restrict__ step_size,
                          const unsigned short* __restrict__ w1t,  // [d][h]
                          const unsigned short* __restrict__ w2b,  // [d][h]
                          const unsigned short* __restrict__ w1b,  // [h][d]
                          const unsigned short* __restrict__ Gb,   // [d][d']
                          const float* __restrict__ c2,
                          float* __restrict__ out) {
    __shared__ unsigned char hld[MT * Ddim * 2];   // 16KB: h tile, swizzled
    __shared__ unsigned char dld[MT * Ddim * 2];   // 16KB: dh tile, swizzled

    const int tid  = threadIdx.x;
    const int lane = tid & 63;
    const int wv   = tid >> 6;        // 0..7
    const int mg   = wv >> 2;         // row group 0..1 (16 rows each)
    const int w4   = wv & 3;          // col wave 0..3
    const int lr16 = lane & 15;
    const int lhi  = lane >> 4;       // 0..3
    const int kof  = lhi * 8;
    const int m0   = blockIdx.x * MT;
    const int rowA = mg * 16 + lr16;  // A-fragment row (block-local)

    const f32x4 z4 = {0.f, 0.f, 0.f, 0.f};

    // ---- merged Phase A + B': h = relu(S@W1+b1), u = T@W2^T (both K=1024) ----
    f32x4 acc_h[4], acc_u[4];
    #pragma unroll
    for (int nt = 0; nt < 4; ++nt) { acc_h[nt] = z4; acc_u[nt] = z4; }

    const float* sp0 = state  + (size_t)(m0 + rowA) * Hdim + kof;
    const float* tp0 = target + (size_t)(m0 + rowA) * Hdim + kof;

    for (int kk = 0; kk < Hdim; kk += 32) {
        float4 s0 = *(const float4*)(sp0 + kk);
        float4 s1 = *(const float4*)(sp0 + kk + 4);
        float4 t0 = *(const float4*)(tp0 + kk);
        float4 t1 = *(const float4*)(tp0 + kk + 4);
        bf16x8 aS, aT;
        aS[0] = (short)f2bf(s0.x); aS[1] = (short)f2bf(s0.y);
        aS[2] = (short)f2bf(s0.z); aS[3] = (short)f2bf(s0.w);
        aS[4] = (short)f2bf(s1.x); aS[5] = (short)f2bf(s1.y);
        aS[6] = (short)f2bf(s1.z); aS[7] = (short)f2bf(s1.w);
        aT[0] = (short)f2bf(t0.x); aT[1] = (short)f2bf(t0.y);
        aT[2] = (short)f2bf(t0.z); aT[3] = (short)f2bf(t0.w);
        aT[4] = (short)f2bf(t1.x); aT[5] = (short)f2bf(t1.y);
        aT[6] = (short)f2bf(t1.z); aT[7] = (short)f2bf(t1.w);
        #pragma unroll
        for (int nt = 0; nt < 4; ++nt) {
            int col = w4 * 64 + nt * 16 + lr16;
            bf16x8 bw1 = *(const bf16x8*)(w1t + (size_t)col * Hdim + kk + kof);
            acc_h[nt] = __builtin_amdgcn_mfma_f32_16x16x32_bf16(aS, bw1, acc_h[nt], 0, 0, 0);
            bf16x8 bw2 = *(const bf16x8*)(w2b + (size_t)col * Hdim + kk + kof);
            acc_u[nt] = __builtin_amdgcn_mfma_f32_16x16x32_bf16(aT, bw2, acc_u[nt], 0, 0, 0);
        }
    }

    // epilogue A: relu + register mask + store h to LDS
    unsigned mask = 0;
    #pragma unroll
    for (int nt = 0; nt < 4; ++nt) {
        int colg = w4 * 64 + nt * 16 + lr16;
        float bias = b1[colg];
        #pragma unroll
        for (int i = 0; i < 4; ++i) {
            int row = mg * 16 + lhi * 4 + i;
            float z = acc_h[nt][i] + bias;
            if (z > 0.f) mask |= 1u << (nt * 4 + i);
            float hv = z > 0.f ? z : 0.f;
            unsigned off = ((unsigned)(row * Ddim + colg) * 2u) ^ (unsigned)((row & 7) << 4);
            *(unsigned short*)(hld + off) = f2bf(hv);
        }
    }
    __syncthreads();

    // ---- Phase C': dh = (h@G + c2 - u) .* mask  -> dld ----
    f32x4 acc_d[4];
    #pragma unroll
    for (int nt = 0; nt < 4; ++nt) {
        int colg = w4 * 64 + nt * 16 + lr16;
        float c2v = c2[colg];
        #pragma unroll
        for (int i = 0; i < 4; ++i) acc_d[nt][i] = c2v - acc_u[nt][i];
    }
    #pragma unroll
    for (int kk = 0; kk < Ddim; kk += 32) {
        unsigned offa = ((unsigned)(rowA * Ddim + kk + kof) * 2u) ^ (unsigned)((rowA & 7) << 4);
        bf16x8 aH = *(const bf16x8*)(hld + offa);
        #pragma unroll
        for (int nt = 0; nt < 4; ++nt) {
            int col = w4 * 64 + nt * 16 + lr16;
            bf16x8 bG = *(const bf16x8*)(Gb + (size_t)col * Ddim + kk + kof);
            acc_d[nt] = __builtin_amdgcn_mfma_f32_16x16x32_bf16(aH, bG, acc_d[nt], 0, 0, 0);
        }
    }
    #pragma unroll
    for (int nt = 0; nt < 4; ++nt) {
        int colg = w4 * 64 + nt * 16 + lr16;
        #pragma unroll
        for (int i = 0; i < 4; ++i) {
            int row = mg * 16 + lhi * 4 + i;
            float dh = ((mask >> (nt * 4 + i)) & 1u) ? acc_d[nt][i] : 0.f;
            unsigned off = ((unsigned)(row * Ddim + colg) * 2u) ^ (unsigned)((row & 7) << 4);
            *(unsigned short*)(dld + off) = f2bf(dh);
        }
    }
    __syncthreads();

    // ---- Phase D: out = S - c * (dh @ W1^T) ----
    const float cc = step_size[0] * (2.0f / (float)((long long)NTOK * Hdim));
    bf16x8 aD[8];
    #pragma unroll
    for (int kq = 0; kq < 8; ++kq) {
        unsigned off = ((unsigned)(rowA * Ddim + kq * 32 + kof) * 2u) ^ (unsigned)((rowA & 7) << 4);
        aD[kq] = *(const bf16x8*)(dld + off);
    }
    for (int nc = 0; nc < 4; ++nc) {
        const int cb = w4 * 256 + nc * 64;
        f32x4 acc[4];
        #pragma unroll
        for (int nt = 0; nt < 4; ++nt) acc[nt] = z4;
        #pragma unroll
        for (int kq = 0; kq < 8; ++kq) {
            #pragma unroll
            for (int nt = 0; nt < 4; ++nt) {
                int col = cb + nt * 16 + lr16;
                bf16x8 bW = *(const bf16x8*)(w1b + (size_t)col * Ddim + kq * 32 + kof);
                acc[nt] = __builtin_amdgcn_mfma_f32_16x16x32_bf16(aD[kq], bW, acc[nt], 0, 0, 0);
            }
        }
        #pragma unroll
        for (int nt = 0; nt < 4; ++nt) {
            int colg = cb + nt * 16 + lr16;
            #pragma unroll
            for (int i = 0; i < 4; ++i) {
                int row = mg * 16 + lhi * 4 + i;
                size_t gi = (size_t)(m0 + row) * Hdim + colg;
                out[gi] = state[gi] - cc * acc[nt][i];
            }
        }
    }
}

extern "C" void kernel_launch(void* const* d_in, const int* in_sizes, int n_in,
                              void* d_out, int out_size, void* d_ws, size_t ws_size,
                              hipStream_t stream) {
    const float* state     = (const float*)d_in[0];
    const float* target    = (const float*)d_in[1];
    const float* W1        = (const float*)d_in[2];
    const float* b1        = (const float*)d_in[3];
    const float* W2        = (const float*)d_in[4];
    const float* b2        = (const float*)d_in[5];
    const float* step_size = (const float*)d_in[6];
    float* out = (float*)d_out;

    // workspace: w1t | w2b | w1b (bf16, 512KB each) | Gb (128KB) | c2 (1KB)
    unsigned short* w1t = (unsigned short*)d_ws;
    unsigned short* w2b = w1t + Hdim * Ddim;
    unsigned short* w1b = w2b + Hdim * Ddim;
    unsigned short* Gb  = w1b + Hdim * Ddim;
    float*          c2  = (float*)(Gb + Ddim * Ddim);

    hipLaunchKernelGGL(prep_weights, dim3((Hdim * Ddim + 255) / 256), dim3(256), 0, stream,
                       W1, W2, w1t, w2b, w1b);
    hipLaunchKernelGGL(prep_G, dim3(Ddim), dim3(256), 0, stream, W2, b2, Gb, c2);
    hipLaunchKernelGGL(ttt_fused, dim3(NTOK / MT), dim3(512), 0, stream,
                       state, target, b1, step_size, w1t, w2b, w1b, Gb, c2, out);
}

// Round 4
// 581.537 us; speedup vs baseline: 1.3128x; 1.3128x over previous
//
#include <hip/hip_runtime.h>
#include <hip/hip_bf16.h>

// TTT layer, one gradient step, fused, round 3 (resubmit after infra timeout).
// out = S - c * ((relu'(z) .* (h@G + c2 - T@W2^T)) @ W1^T)
//   z = S@W1 + b1, h = relu(z), G = W2@W2^T (symmetric), c2 = W2@b2
//   c = lr*2/(B*T*H). Stability gradient is zero at step 1.
// Structure: 1 block/CU (grid 256), MT=128 tokens, LDS-staged K-chunks,
// T14 issue-early/write-late, all MFMA operands from swizzled LDS.

#define Hdim 1024
#define Ddim 256
#define NTOK 32768
#define MT   128
#define KC   64

typedef __attribute__((ext_vector_type(8))) short bf16x8;
typedef __attribute__((ext_vector_type(4))) float f32x4;
typedef __attribute__((ext_vector_type(4))) unsigned int u32x4;
typedef unsigned short ushort_t;

static __device__ __forceinline__ unsigned short f2bf(float f) {
    unsigned u = __builtin_bit_cast(unsigned, f);
    u += 0x7FFFu + ((u >> 16) & 1u);          // RNE
    return (unsigned short)(u >> 16);
}

static __device__ __forceinline__ bf16x8 pack8(float4 a, float4 b) {
    bf16x8 v;
    v[0] = (short)f2bf(a.x); v[1] = (short)f2bf(a.y);
    v[2] = (short)f2bf(a.z); v[3] = (short)f2bf(a.w);
    v[4] = (short)f2bf(b.x); v[5] = (short)f2bf(b.y);
    v[6] = (short)f2bf(b.z); v[7] = (short)f2bf(b.w);
    return v;
}

static __device__ __forceinline__ unsigned swz(unsigned byte_off, int row) {
    return byte_off ^ ((unsigned)(row & 7) << 4);
}

// ---------- prep 1: straight convert-copies (w1b=[h][d], w2b=[d][h]) ----------
__global__ void prep_copy(const float* __restrict__ W1, const float* __restrict__ W2,
                          ushort_t* __restrict__ w1b, ushort_t* __restrict__ w2b) {
    int i = (blockIdx.x * 256 + threadIdx.x) * 8;
    if (i >= Hdim * Ddim) return;
    float4 a0 = *(const float4*)(W1 + i), a1 = *(const float4*)(W1 + i + 4);
    *(bf16x8*)(w1b + i) = pack8(a0, a1);
    float4 c0 = *(const float4*)(W2 + i), c1 = *(const float4*)(W2 + i + 4);
    *(bf16x8*)(w2b + i) = pack8(c0, c1);
}

// ---------- prep 2: LDS-tiled transpose w1t[d][h] = W1[h][d] ----------
__global__ void prep_t(const float* __restrict__ W1, ushort_t* __restrict__ w1t) {
    __shared__ ushort_t tile[64][72];
    const int h0 = blockIdx.x * 64, d0 = blockIdx.y * 64;
    const int t = threadIdx.x;             // 256
    const int r = t >> 2, c4 = (t & 3) * 16;
    #pragma unroll
    for (int j = 0; j < 4; ++j) {
        float4 v = *(const float4*)(W1 + (size_t)(h0 + r) * Ddim + d0 + c4 + j * 4);
        tile[r][c4 + j * 4 + 0] = f2bf(v.x);
        tile[r][c4 + j * 4 + 1] = f2bf(v.y);
        tile[r][c4 + j * 4 + 2] = f2bf(v.z);
        tile[r][c4 + j * 4 + 3] = f2bf(v.w);
    }
    __syncthreads();
    const int dr = t >> 2, hc = (t & 3) * 16;
    bf16x8 o0, o1;
    #pragma unroll
    for (int j = 0; j < 8; ++j) o0[j] = (short)tile[hc + j][dr];
    #pragma unroll
    for (int j = 0; j < 8; ++j) o1[j] = (short)tile[hc + 8 + j][dr];
    *(bf16x8*)(w1t + (size_t)(d0 + dr) * Hdim + h0 + hc)     = o0;
    *(bf16x8*)(w1t + (size_t)(d0 + dr) * Hdim + h0 + hc + 8) = o1;
}

// ---------- prep 3: G = W2@W2^T via MFMA (grid 2), + c2 = W2@b2 ----------
__launch_bounds__(512, 2)
__global__ void prep_G(const ushort_t* __restrict__ w2b, const float* __restrict__ W2,
                       const float* __restrict__ b2, ushort_t* __restrict__ Gb,
                       float* __restrict__ c2) {
    const int tid = threadIdx.x, lane = tid & 63, wv = tid >> 6;
    const int lr16 = lane & 15, lhi = lane >> 4;
    const int rbase = blockIdx.x * 128 + (wv >> 2) * 64;   // M-split across 2 blocks
    const int ngb = (wv & 3) * 64;
    const f32x4 z4 = {0.f, 0.f, 0.f, 0.f};
    f32x4 acc[4][4];
    #pragma unroll
    for (int mt = 0; mt < 4; ++mt)
        #pragma unroll
        for (int nt = 0; nt < 4; ++nt) acc[mt][nt] = z4;
    #pragma unroll 4
    for (int kk = 0; kk < 32; ++kk) {
        bf16x8 aA[4], bB[4];
        #pragma unroll
        for (int mt = 0; mt < 4; ++mt)
            aA[mt] = *(const bf16x8*)(w2b + (size_t)(rbase + mt * 16 + lr16) * Hdim + kk * 32 + lhi * 8);
        #pragma unroll
        for (int nt = 0; nt < 4; ++nt)
            bB[nt] = *(const bf16x8*)(w2b + (size_t)(ngb + nt * 16 + lr16) * Hdim + kk * 32 + lhi * 8);
        #pragma unroll
        for (int mt = 0; mt < 4; ++mt)
            #pragma unroll
            for (int nt = 0; nt < 4; ++nt)
                acc[mt][nt] = __builtin_amdgcn_mfma_f32_16x16x32_bf16(aA[mt], bB[nt], acc[mt][nt], 0, 0, 0);
    }
    #pragma unroll
    for (int mt = 0; mt < 4; ++mt)
        #pragma unroll
        for (int nt = 0; nt < 4; ++nt) {
            int col = ngb + nt * 16 + lr16;
            #pragma unroll
            for (int i = 0; i < 4; ++i) {
                int row = rbase + mt * 16 + lhi * 4 + i;
                Gb[row * Ddim + col] = f2bf(acc[mt][nt][i]);
            }
        }
    if (blockIdx.x == 0 && tid < 256) {
        const float* wp = W2 + (size_t)tid * Hdim;
        float s0 = 0.f, s1 = 0.f;
        for (int h = 0; h < Hdim; h += 8) {
            float4 a = *(const float4*)(wp + h), b = *(const float4*)(wp + h + 4);
            float4 x = *(const float4*)(b2 + h), y = *(const float4*)(b2 + h + 4);
            s0 += a.x * x.x + a.y * x.y + a.z * x.z + a.w * x.w;
            s1 += b.x * y.x + b.y * y.y + b.z * y.z + b.w * y.w;
        }
        c2[tid] = s0 + s1;
    }
}

// ---------- fused TTT kernel ----------
__launch_bounds__(512, 2)
__global__ void ttt_fused(const float* __restrict__ state,
                          const float* __restrict__ target,
                          const float* __restrict__ b1g,
                          const float* __restrict__ step_size,
                          const ushort_t* __restrict__ w1t,  // [d][h]
                          const ushort_t* __restrict__ w2b,  // [d][h]
                          const ushort_t* __restrict__ w1b,  // [h][d]
                          const ushort_t* __restrict__ Gb,   // [d][d']
                          const float* __restrict__ c2,
                          float* __restrict__ out) {
    __shared__ __align__(16) char smem[131072];
    char* const sS  = smem;             // [128][64] bf16, 16KB (rows 128B, swizzled)
    char* const sT  = smem + 16384;     // 16KB
    char* const sW1 = smem + 32768;     // [256][64] bf16, 32KB
    char* const sW2 = smem + 65536;     // 32KB
    char* const hls = smem;             // phase C: h  [128][256] bf16, 64KB (rows 512B)
    char* const dls = smem + 65536;     // phase D: dh [128][256] bf16, 64KB

    const int tid  = threadIdx.x;
    const int lane = tid & 63;
    const int wv   = tid >> 6;          // 0..7
    const int mgb  = (wv >> 2) * 64;    // row-group base (2 groups of 64)
    const int ng   = wv & 3;
    const int ngb  = ng * 64;           // col-group base (4 groups of 64)
    const int lr16 = lane & 15;
    const int lhi  = lane >> 4;
    const int m0   = blockIdx.x * MT;

    // staging thread mapping
    const int srow = tid >> 2;              // 0..127
    const int sc4  = (tid & 3) * 16;        // float offset in chunk row
    const int wrow = tid >> 1;              // 0..255
    const int wce  = (tid & 1) * 32;        // bf16-elem offset in chunk row
    const float* const spS = state  + (size_t)(m0 + srow) * Hdim + sc4;
    const float* const spT = target + (size_t)(m0 + srow) * Hdim + sc4;
    const ushort_t* const wpA = w1t + (size_t)wrow * Hdim + wce;
    const ushort_t* const wpB = w2b + (size_t)wrow * Hdim + wce;
    const unsigned offS0 = swz((unsigned)(srow * 128 + sc4 * 2), srow);
    const unsigned offS1 = swz((unsigned)(srow * 128 + sc4 * 2 + 16), srow);
    unsigned offW[4];
    #pragma unroll
    for (int j = 0; j < 4; ++j) offW[j] = swz((unsigned)(wrow * 128 + wce * 2 + j * 16), wrow);

    const f32x4 z4 = {0.f, 0.f, 0.f, 0.f};
    f32x4 acc_h[4][4], acc_u[4][4];
    #pragma unroll
    for (int mt = 0; mt < 4; ++mt)
        #pragma unroll
        for (int nt = 0; nt < 4; ++nt) { acc_h[mt][nt] = z4; acc_u[mt][nt] = z4; }

    float4 ps[4], pt[4];

#define ISSUE(kc) { \
    _Pragma("unroll") for (int j = 0; j < 4; ++j) ps[j] = *(const float4*)(spS + (kc) * KC + j * 4); \
    _Pragma("unroll") for (int j = 0; j < 4; ++j) pt[j] = *(const float4*)(spT + (kc) * KC + j * 4); }

#define STAGE(kc) { \
    u32x4 pw[8]; \
    _Pragma("unroll") for (int j = 0; j < 4; ++j) pw[j]     = *(const u32x4*)(wpA + (kc) * KC + j * 8); \
    _Pragma("unroll") for (int j = 0; j < 4; ++j) pw[4 + j] = *(const u32x4*)(wpB + (kc) * KC + j * 8); \
    *(bf16x8*)(sS + offS0) = pack8(ps[0], ps[1]); \
    *(bf16x8*)(sS + offS1) = pack8(ps[2], ps[3]); \
    *(bf16x8*)(sT + offS0) = pack8(pt[0], pt[1]); \
    *(bf16x8*)(sT + offS1) = pack8(pt[2], pt[3]); \
    _Pragma("unroll") for (int j = 0; j < 4; ++j) *(u32x4*)(sW1 + offW[j]) = pw[j]; \
    _Pragma("unroll") for (int j = 0; j < 4; ++j) *(u32x4*)(sW2 + offW[j]) = pw[4 + j]; }

#define COMPUTE() { \
    _Pragma("unroll") for (int kk = 0; kk < 2; ++kk) { \
        bf16x8 aS[4], aT[4], b1v[4], b2v[4]; \
        _Pragma("unroll") for (int mt = 0; mt < 4; ++mt) { \
            int r = mgb + mt * 16 + lr16; \
            unsigned off = swz((unsigned)(r * 128 + kk * 64 + lhi * 16), r); \
            aS[mt] = *(const bf16x8*)(sS + off); \
            aT[mt] = *(const bf16x8*)(sT + off); \
        } \
        _Pragma("unroll") for (int nt = 0; nt < 4; ++nt) { \
            int c = ngb + nt * 16 + lr16; \
            unsigned off = swz((unsigned)(c * 128 + kk * 64 + lhi * 16), c); \
            b1v[nt] = *(const bf16x8*)(sW1 + off); \
            b2v[nt] = *(const bf16x8*)(sW2 + off); \
        } \
        _Pragma("unroll") for (int mt = 0; mt < 4; ++mt) \
            _Pragma("unroll") for (int nt = 0; nt < 4; ++nt) { \
                acc_h[mt][nt] = __builtin_amdgcn_mfma_f32_16x16x32_bf16(aS[mt], b1v[nt], acc_h[mt][nt], 0, 0, 0); \
                acc_u[mt][nt] = __builtin_amdgcn_mfma_f32_16x16x32_bf16(aT[mt], b2v[nt], acc_u[mt][nt], 0, 0, 0); \
            } \
    } }

    // ---- phase AB: h = relu(S@W1+b1) (acc_h), u = T@W2^T (acc_u), K=1024 ----
    ISSUE(0);
    STAGE(0);
    ISSUE(1);
    __syncthreads();
    for (int kc = 0; kc < Hdim / KC; ++kc) {
        COMPUTE();
        __syncthreads();
        if (kc < Hdim / KC - 1) {
            STAGE(kc + 1);
            if (kc < Hdim / KC - 2) ISSUE(kc + 2);
            __syncthreads();
        }
    }

    // ---- h epilogue: bias+relu, mask in regs, h -> LDS ----
    unsigned long long mask = 0ULL;
    {
        float bia[4];
        #pragma unroll
        for (int nt = 0; nt < 4; ++nt) bia[nt] = b1g[ngb + nt * 16 + lr16];
        #pragma unroll
        for (int mt = 0; mt < 4; ++mt)
            #pragma unroll
            for (int nt = 0; nt < 4; ++nt) {
                int col = ngb + nt * 16 + lr16;
                #pragma unroll
                for (int i = 0; i < 4; ++i) {
                    int row = mgb + mt * 16 + lhi * 4 + i;
                    float z = acc_h[mt][nt][i] + bia[nt];
                    float hv = z > 0.f ? z : 0.f;
                    if (z > 0.f) mask |= 1ULL << (mt * 16 + nt * 4 + i);
                    *(ushort_t*)(hls + swz((unsigned)(row * 512 + col * 2), row)) = f2bf(hv);
                }
            }
    }
    __syncthreads();

    // ---- phase C': dh = (h@G + c2 - u) .* mask -> LDS ----
    {
        f32x4 acc_d[4][4];
        #pragma unroll
        for (int nt = 0; nt < 4; ++nt) {
            float cv = c2[ngb + nt * 16 + lr16];
            #pragma unroll
            for (int mt = 0; mt < 4; ++mt)
                #pragma unroll
                for (int i = 0; i < 4; ++i) acc_d[mt][nt][i] = cv - acc_u[mt][nt][i];
        }
        #pragma unroll
        for (int kk = 0; kk < 8; ++kk) {
            bf16x8 aH[4], bG[4];
            #pragma unroll
            for (int mt = 0; mt < 4; ++mt) {
                int r = mgb + mt * 16 + lr16;
                aH[mt] = *(const bf16x8*)(hls + swz((unsigned)(r * 512 + kk * 64 + lhi * 16), r));
            }
            #pragma unroll
            for (int nt = 0; nt < 4; ++nt) {
                int c = ngb + nt * 16 + lr16;
                bG[nt] = *(const bf16x8*)(Gb + (size_t)c * Ddim + kk * 32 + lhi * 8);
            }
            #pragma unroll
            for (int mt = 0; mt < 4; ++mt)
                #pragma unroll
                for (int nt = 0; nt < 4; ++nt)
                    acc_d[mt][nt] = __builtin_amdgcn_mfma_f32_16x16x32_bf16(aH[mt], bG[nt], acc_d[mt][nt], 0, 0, 0);
        }
        #pragma unroll
        for (int mt = 0; mt < 4; ++mt)
            #pragma unroll
            for (int nt = 0; nt < 4; ++nt) {
                int col = ngb + nt * 16 + lr16;
                #pragma unroll
                for (int i = 0; i < 4; ++i) {
                    int row = mgb + mt * 16 + lhi * 4 + i;
                    float v = ((mask >> (mt * 16 + nt * 4 + i)) & 1ULL) ? acc_d[mt][nt][i] : 0.f;
                    *(ushort_t*)(dls + swz((unsigned)(row * 512 + col * 2), row)) = f2bf(v);
                }
            }
    }
    __syncthreads();

    // ---- phase D: out = S - c * (dh @ W1^T) ----
    {
        const float cc = step_size[0] * (2.0f / ((float)NTOK * (float)Hdim));
        for (int nc = 0; nc < 4; ++nc) {
            const int cb = ng * 256 + nc * 64;
            f32x4 acc[4][4];
            #pragma unroll
            for (int mt = 0; mt < 4; ++mt)
                #pragma unroll
                for (int nt = 0; nt < 4; ++nt) acc[mt][nt] = z4;
            #pragma unroll
            for (int kq = 0; kq < 8; ++kq) {
                bf16x8 aD[4], bW[4];
                #pragma unroll
                for (int mt = 0; mt < 4; ++mt) {
                    int r = mgb + mt * 16 + lr16;
                    aD[mt] = *(const bf16x8*)(dls + swz((unsigned)(r * 512 + kq * 64 + lhi * 16), r));
                }
                #pragma unroll
                for (int nt = 0; nt < 4; ++nt) {
                    int c = cb + nt * 16 + lr16;
                    bW[nt] = *(const bf16x8*)(w1b + (size_t)c * Ddim + kq * 32 + lhi * 8);
                }
                #pragma unroll
                for (int mt = 0; mt < 4; ++mt)
                    #pragma unroll
                    for (int nt = 0; nt < 4; ++nt)
                        acc[mt][nt] = __builtin_amdgcn_mfma_f32_16x16x32_bf16(aD[mt], bW[nt], acc[mt][nt], 0, 0, 0);
            }
            #pragma unroll
            for (int nt = 0; nt < 4; ++nt) {
                int col = cb + nt * 16 + lr16;
                #pragma unroll
                for (int mt = 0; mt < 4; ++mt)
                    #pragma unroll
                    for (int i = 0; i < 4; ++i) {
                        int row = mgb + mt * 16 + lhi * 4 + i;
                        size_t gi = (size_t)(m0 + row) * Hdim + col;
                        out[gi] = state[gi] - cc * acc[mt][nt][i];
                    }
            }
        }
    }
#undef ISSUE
#undef STAGE
#undef COMPUTE
}

extern "C" void kernel_launch(void* const* d_in, const int* in_sizes, int n_in,
                              void* d_out, int out_size, void* d_ws, size_t ws_size,
                              hipStream_t stream) {
    const float* state     = (const float*)d_in[0];
    const float* target    = (const float*)d_in[1];
    const float* W1        = (const float*)d_in[2];
    const float* b1        = (const float*)d_in[3];
    const float* W2        = (const float*)d_in[4];
    const float* b2        = (const float*)d_in[5];
    const float* step_size = (const float*)d_in[6];
    float* out = (float*)d_out;

    // ws: w1t | w1b | w2b (512KB each) | Gb (128KB) | c2 (1KB)
    ushort_t* w1t = (ushort_t*)d_ws;
    ushort_t* w1b = w1t + Hdim * Ddim;
    ushort_t* w2b = w1b + Hdim * Ddim;
    ushort_t* Gb  = w2b + Hdim * Ddim;
    float*    c2  = (float*)(Gb + Ddim * Ddim);

    hipLaunchKernelGGL(prep_copy, dim3(Hdim * Ddim / 8 / 256), dim3(256), 0, stream, W1, W2, w1b, w2b);
    hipLaunchKernelGGL(prep_t, dim3(Hdim / 64, Ddim / 64), dim3(256), 0, stream, W1, w1t);
    hipLaunchKernelGGL(prep_G, dim3(2), dim3(512), 0, stream, w2b, W2, b2, Gb, c2);
    hipLaunchKernelGGL(ttt_fused, dim3(NTOK / MT), dim3(512), 0, stream,
                       state, target, b1, step_size, w1t, w2b, w1b, Gb, c2, out);
}